// Round 13
// baseline (172.901 us; speedup 1.0000x reference)
//
#include <hip/hip_runtime.h>

#define B 128
#define N 65536
#define D 512
#define K 5
#define M 256              // D * RATIO
#define GPB 256            // gallery rows per block (kernel1)
#define NBLK1 (N / GPB)    // 256 blocks
#define CHR 16             // g-rows per chunk (full D each)
#define NCHK (GPB / CHR)   // 16

typedef __attribute__((ext_vector_type(8))) short short8;
typedef __attribute__((ext_vector_type(4))) float f32x4;
typedef __attribute__((address_space(1))) const unsigned char as1cu8;
typedef __attribute__((address_space(3))) unsigned char as3u8;

// pack two fp32 -> one u32 of 2 bf16 (truncation) via v_perm_b32.
__device__ __forceinline__ unsigned int pack_bf2(float lo, float hi) {
    return __builtin_amdgcn_perm(__float_as_uint(hi), __float_as_uint(lo), 0x07060302u);
}

__device__ __forceinline__ void top5_insert(float v, int gi, float tv[K], int ti[K]) {
    // descending by value, ties broken by lower index (matches lax.top_k)
    if (v > tv[K - 1] || (v == tv[K - 1] && gi < ti[K - 1])) {
        tv[K - 1] = v; ti[K - 1] = gi;
        #pragma unroll
        for (int k = K - 1; k > 0; --k) {
            bool sw = (tv[k] > tv[k - 1]) || (tv[k] == tv[k - 1] && ti[k] < ti[k - 1]);
            if (sw) {
                float fv = tv[k]; tv[k] = tv[k - 1]; tv[k - 1] = fv;
                int fi = ti[k]; ti[k] = ti[k - 1]; ti[k - 1] = fi;
            }
        }
    }
}

// packed-score insert (meta lives in low 8 mantissa bits; candidates distinct)
__device__ __forceinline__ void pk_insert(float sp, float lst[K]) {
    if (sp > lst[K - 1]) {
        lst[K - 1] = sp;
        #pragma unroll
        for (int k = K - 1; k > 0; --k)
            if (lst[k] > lst[k - 1]) {
                float t2 = lst[k]; lst[k] = lst[k - 1]; lst[k - 1] = t2;
            }
    }
}

// k1: fp32 gallery streamed via global_load_lds into a 4-deep LDS ring with
// COUNTED vmcnt waits + raw s_barrier (T3/T4; m201 template). R12 lesson:
// __syncthreads() drains vmcnt(0) and exposes full DMA latency every chunk.
// Here chunks c+1, c+2 stay in flight across each barrier (vmcnt(8)).
// 8 waves; wave w owns b-tile w (16 b-rows, full K=512 in 64 VGPRs of
// t-fragments). Chunk = 16 g-rows x full D. DMA source pre-XOR-swizzled
// within 128B groups (rule #21); ds_read applies the same XOR.
__global__ __launch_bounds__(512, 2) void k1_sims(const float* __restrict__ t_f,
                                                  const float* __restrict__ gal,
                                                  float2* __restrict__ partial) {
    __shared__ __align__(16) char gbuf[4][CHR * 2048];   // 131072 B ring

    const int tid = threadIdx.x;
    const int blk = blockIdx.x;
    const int lane = tid & 63;
    const int w = tid >> 6;          // b-tile
    const int l15 = lane & 15;
    const int l4 = lane >> 4;
    const int xr = (l15 & 7) << 4;

    const char* gal_b = reinterpret_cast<const char*>(gal);
    const size_t rowbase = ((size_t)blk * GPB) * 2048;

    // wave w stages chunk rows {2w, 2w+1}: 4 x 1KB contiguous DMA per chunk
#define DMA(c, bi) do { \
        _Pragma("unroll") \
        for (int i_ = 0; i_ < 4; ++i_) { \
            const int rl_ = 2 * w + (i_ >> 1); \
            const char* s_ = gal_b + rowbase + ((size_t)(c) * CHR + rl_) * 2048 \
                             + (i_ & 1) * 1024 + ((lane * 16) ^ ((rl_ & 7) << 4)); \
            char* d_ = &gbuf[bi][rl_ * 2048 + (i_ & 1) * 1024]; \
            __builtin_amdgcn_global_load_lds((as1cu8*)s_, (as3u8*)d_, 16, 0, 0); \
        } \
    } while (0)

    // prologue: 3 chunks in flight (12 vm-ops/wave)
    DMA(0, 0);
    DMA(1, 1);
    DMA(2, 2);

    // t-fragments: lane holds t[w*16 + l15][ks*32 + l4*8 ..+8], full K. 64 VGPR.
    short8 tfr[16];
    {
        const float* tp = t_f + (size_t)(w * 16 + l15) * D + l4 * 8;
        #pragma unroll
        for (int ks = 0; ks < 16; ++ks) {
            float4 a = *reinterpret_cast<const float4*>(tp + ks * 32);
            float4 b = *reinterpret_cast<const float4*>(tp + ks * 32 + 4);
            uint4 q;
            q.x = pack_bf2(a.x, a.y); q.y = pack_bf2(a.z, a.w);
            q.z = pack_bf2(b.x, b.y); q.w = pack_bf2(b.z, b.w);
            tfr[ks] = *reinterpret_cast<short8*>(&q);
        }
    }

    float lst[K];
    #pragma unroll
    for (int k = 0; k < K; ++k) lst[k] = -1e30f;

    // compute chunk c: full K for 16 g-rows vs wave's 16 b-rows.
    // C layout: row (g) = l4*4+r, col (b) = l15.
#define COMPUTE(c) do { \
        f32x4 acc_ = (f32x4)0.0f; \
        float nrm_ = 0.0f; \
        const char* gb_ = &gbuf[(c) & 3][0]; \
        _Pragma("unroll") \
        for (int ks_ = 0; ks_ < 16; ++ks_) { \
            const int co_ = ks_ * 128 + l4 * 32; \
            float4 a0_ = *reinterpret_cast<const float4*>(gb_ + l15 * 2048 + (co_ ^ xr)); \
            float4 a1_ = *reinterpret_cast<const float4*>(gb_ + l15 * 2048 + ((co_ + 16) ^ xr)); \
            nrm_ = fmaf(a0_.x, a0_.x, nrm_); nrm_ = fmaf(a0_.y, a0_.y, nrm_); \
            nrm_ = fmaf(a0_.z, a0_.z, nrm_); nrm_ = fmaf(a0_.w, a0_.w, nrm_); \
            nrm_ = fmaf(a1_.x, a1_.x, nrm_); nrm_ = fmaf(a1_.y, a1_.y, nrm_); \
            nrm_ = fmaf(a1_.z, a1_.z, nrm_); nrm_ = fmaf(a1_.w, a1_.w, nrm_); \
            uint4 q_; \
            q_.x = pack_bf2(a0_.x, a0_.y); q_.y = pack_bf2(a0_.z, a0_.w); \
            q_.z = pack_bf2(a1_.x, a1_.y); q_.w = pack_bf2(a1_.z, a1_.w); \
            short8 af_ = *reinterpret_cast<short8*>(&q_); \
            acc_ = __builtin_amdgcn_mfma_f32_16x16x32_bf16(af_, tfr[ks_], acc_, 0, 0, 0); \
        } \
        nrm_ += __shfl_xor(nrm_, 16); \
        nrm_ += __shfl_xor(nrm_, 32); \
        float invn_ = rsqrtf(fmaxf(nrm_, 1e-24f)); \
        _Pragma("unroll") \
        for (int r_ = 0; r_ < 4; ++r_) { \
            float s_ = acc_[r_] * __shfl(invn_, l4 * 4 + r_); \
            unsigned meta_ = (unsigned)((c) * CHR + l4 * 4 + r_); \
            float sp_ = __uint_as_float((__float_as_uint(s_) & 0xFFFFFF00u) | meta_); \
            pk_insert(sp_, lst); \
        } \
    } while (0)

    // counted-vmcnt iteration: chunk c ready when <= 2*4 ops outstanding.
#define ITER(c, vmn) \
    asm volatile("s_waitcnt vmcnt(" #vmn ")" ::: "memory"); \
    __builtin_amdgcn_sched_barrier(0); \
    __builtin_amdgcn_s_barrier(); \
    __builtin_amdgcn_sched_barrier(0); \
    if ((c) + 3 < NCHK) DMA((c) + 3, ((c) + 3) & 3); \
    COMPUTE(c);

    ITER(0, 8)  ITER(1, 8)  ITER(2, 8)  ITER(3, 8)
    ITER(4, 8)  ITER(5, 8)  ITER(6, 8)  ITER(7, 8)
    ITER(8, 8)  ITER(9, 8)  ITER(10, 8) ITER(11, 8)
    ITER(12, 8) ITER(13, 8) ITER(14, 4) ITER(15, 0)

#undef ITER
#undef COMPUTE
#undef DMA

    // merge per-b lists across the 4 l4 lanes (same b = w*16+l15)
    #pragma unroll
    for (int mk = 16; mk <= 32; mk <<= 1) {
        float inc[K];
        #pragma unroll
        for (int k = 0; k < K; ++k) inc[k] = __shfl_xor(lst[k], mk);
        #pragma unroll
        for (int k = 0; k < K; ++k) pk_insert(inc[k], lst);
    }

    if (l4 == 0) {
        const int b = w * 16 + l15;
        #pragma unroll
        for (int k = 0; k < K; ++k) {
            unsigned sp = __float_as_uint(lst[k]);
            int g = blk * GPB + (int)(sp & 0xFFu);
            partial[((size_t)b * NBLK1 + blk) * K + k] = make_float2(lst[k], __int_as_float(g));
        }
    }
}

// k2: merge 256 partial top-5 lists per batch row -> top_idx. Shuffle-first.
__global__ __launch_bounds__(512) void k2_merge(const float2* __restrict__ partial,
                                                int* __restrict__ top_idx) {
    __shared__ float2 wlist[8][K];
    const int b = blockIdx.x;
    const int p = threadIdx.x;
    const int lane = p & 63;
    const int w = p >> 6;

    float mv[K]; int mi[K];
    #pragma unroll
    for (int k = 0; k < K; ++k) { mv[k] = -1e30f; mi[k] = 0x7fffffff; }
    if (p < NBLK1) {
        #pragma unroll
        for (int k = 0; k < K; ++k) {
            float2 c = partial[((size_t)b * NBLK1 + p) * K + k];
            mv[k] = c.x; mi[k] = __float_as_int(c.y);
        }
    }
    #pragma unroll
    for (int mk = 1; mk <= 32; mk <<= 1) {
        float ov[K]; int oi[K];
        #pragma unroll
        for (int k = 0; k < K; ++k) { ov[k] = __shfl_xor(mv[k], mk); oi[k] = __shfl_xor(mi[k], mk); }
        #pragma unroll
        for (int k = 0; k < K; ++k) top5_insert(ov[k], oi[k], mv, mi);
    }
    if (lane == 0) {
        #pragma unroll
        for (int k = 0; k < K; ++k) wlist[w][k] = make_float2(mv[k], __int_as_float(mi[k]));
    }
    __syncthreads();
    if (w == 0) {
        #pragma unroll
        for (int k = 0; k < K; ++k) { mv[k] = -1e30f; mi[k] = 0x7fffffff; }
        if (lane < 8) {
            #pragma unroll
            for (int k = 0; k < K; ++k) {
                float2 c = wlist[lane][k];
                mv[k] = c.x; mi[k] = __float_as_int(c.y);
            }
        }
        #pragma unroll
        for (int mk = 1; mk <= 4; mk <<= 1) {
            float ov[K]; int oi[K];
            #pragma unroll
            for (int k = 0; k < K; ++k) { ov[k] = __shfl_xor(mv[k], mk); oi[k] = __shfl_xor(mi[k], mk); }
            #pragma unroll
            for (int k = 0; k < K; ++k) top5_insert(ov[k], oi[k], mv, mi);
        }
        if (lane == 0) {
            #pragma unroll
            for (int k = 0; k < K; ++k) top_idx[b * K + k] = mi[k];
        }
    }
}

// k3: one block per (b,k) row: bottom-m membership of |gal[row,c]*s_f[b,c]|
// (per-row norms are positive constants -> ordering matches the reference's
// normalized products). Plain stores; kernel-boundary coherence (R8 lesson).
__global__ __launch_bounds__(512) void k3_member(const float* __restrict__ s_f,
                                                 const float* __restrict__ gal,
                                                 const int* __restrict__ top_idx,
                                                 unsigned long long* __restrict__ bkmask) {
    __shared__ __align__(16) float pS[D];
    const int p = threadIdx.x;
    const int bk = blockIdx.x;
    const int b = bk / K;
    const int row = top_idx[bk];
    float pv = fabsf(gal[(size_t)row * D + p] * s_f[(size_t)b * D + p]);
    pS[p] = pv;
    __syncthreads();
    int cnt = 0;
    const float4* p4 = reinterpret_cast<const float4*>(pS);
    #pragma unroll 4
    for (int j = 0; j < D / 4; ++j) {
        float4 o = p4[j];
        cnt += (o.x < pv || (o.x == pv && (4 * j + 0) < p)) ? 1 : 0;
        cnt += (o.y < pv || (o.y == pv && (4 * j + 1) < p)) ? 1 : 0;
        cnt += (o.z < pv || (o.z == pv && (4 * j + 2) < p)) ? 1 : 0;
        cnt += (o.w < pv || (o.w == pv && (4 * j + 3) < p)) ? 1 : 0;
    }
    unsigned long long bm = __ballot(cnt < M);
    if ((p & 63) == 0) bkmask[(size_t)bk * 8 + (p >> 6)] = bm;
}

// k4: AND-reduce the 640 per-(b,k) masks, emit the output mask. 40 KB, L2-hot.
__global__ __launch_bounds__(512) void k4_final(const unsigned long long* __restrict__ bkmask,
                                                float* __restrict__ out) {
    const int c = threadIdx.x;
    const int word = c >> 6, bit = c & 63;
    unsigned long long acc = ~0ull;
    for (int bk = 0; bk < B * K; bk += 4) {
        acc &= bkmask[(size_t)bk * 8 + word];
        acc &= bkmask[(size_t)(bk + 1) * 8 + word];
        acc &= bkmask[(size_t)(bk + 2) * 8 + word];
        acc &= bkmask[(size_t)(bk + 3) * 8 + word];
    }
    out[c] = ((acc >> bit) & 1ull) ? 0.0f : 1.0f;
}

extern "C" void kernel_launch(void* const* d_in, const int* in_sizes, int n_in,
                              void* d_out, int out_size, void* d_ws, size_t ws_size,
                              hipStream_t stream) {
    (void)in_sizes; (void)n_in; (void)out_size; (void)ws_size;
    const float* s_f = (const float*)d_in[0];
    const float* t_f = (const float*)d_in[1];
    const float* gal = (const float*)d_in[2];
    float* out = (float*)d_out;

    char* ws = (char*)d_ws;
    const size_t off_partial = 0;                        // 128*256*5*8 = 1310720
    const size_t off_topidx  = off_partial + 1310720;    // 2560
    const size_t off_bkmask  = off_topidx + 2560;        // 40960

    float2* partial = (float2*)(ws + off_partial);
    int* top_idx = (int*)(ws + off_topidx);
    unsigned long long* bkmask = (unsigned long long*)(ws + off_bkmask);

    hipLaunchKernelGGL(k1_sims, dim3(NBLK1), dim3(512), 0, stream, t_f, gal, partial);
    hipLaunchKernelGGL(k2_merge, dim3(B), dim3(512), 0, stream, partial, top_idx);
    hipLaunchKernelGGL(k3_member, dim3(B * K), dim3(512), 0, stream, s_f, gal, top_idx, bkmask);
    hipLaunchKernelGGL(k4_final, dim3(1), dim3(512), 0, stream, bkmask, out);
}

// Round 14
// 159.097 us; speedup vs baseline: 1.0868x; 1.0868x over previous
//
#include <hip/hip_runtime.h>

#define B 128
#define N 65536
#define D 512
#define K 5
#define M 256              // D * RATIO
#define GPB 256            // gallery rows per block (kernel1)
#define NBLK1 (N / GPB)    // 256 blocks
#define CHR 16             // g-rows per chunk (full D each)
#define NCHK (GPB / CHR)   // 16

typedef __attribute__((ext_vector_type(8))) short short8;
typedef __attribute__((ext_vector_type(4))) float f32x4;
typedef __attribute__((address_space(1))) const unsigned char as1cu8;
typedef __attribute__((address_space(3))) unsigned char as3u8;

// pack two fp32 -> one u32 of 2 bf16 (truncation) via v_perm_b32.
__device__ __forceinline__ unsigned int pack_bf2(float lo, float hi) {
    return __builtin_amdgcn_perm(__float_as_uint(hi), __float_as_uint(lo), 0x07060302u);
}

__device__ __forceinline__ void top5_insert(float v, int gi, float tv[K], int ti[K]) {
    // descending by value, ties broken by lower index (matches lax.top_k)
    if (v > tv[K - 1] || (v == tv[K - 1] && gi < ti[K - 1])) {
        tv[K - 1] = v; ti[K - 1] = gi;
        #pragma unroll
        for (int k = K - 1; k > 0; --k) {
            bool sw = (tv[k] > tv[k - 1]) || (tv[k] == tv[k - 1] && ti[k] < ti[k - 1]);
            if (sw) {
                float fv = tv[k]; tv[k] = tv[k - 1]; tv[k - 1] = fv;
                int fi = ti[k]; ti[k] = ti[k - 1]; ti[k - 1] = fi;
            }
        }
    }
}

// packed-score insert (meta lives in low 8 mantissa bits; candidates distinct)
__device__ __forceinline__ void pk_insert(float sp, float lst[K]) {
    if (sp > lst[K - 1]) {
        lst[K - 1] = sp;
        #pragma unroll
        for (int k = K - 1; k > 0; --k)
            if (lst[k] > lst[k - 1]) {
                float t2 = lst[k]; lst[k] = lst[k - 1]; lst[k - 1] = t2;
            }
    }
}

// k1: R12's 16-wave DMA structure + R13's counted-vmcnt (no drains).
// 16 waves = (b-tile w&7) x (parity w>>3): even waves compute even chunks,
// odd waves odd chunks; t-fragments (full K) resident in 64 VGPRs per wave.
// Ring of 4 x 32KB fp32 chunk buffers filled by global_load_lds (contiguous
// 1KB/inst, source pre-XOR-swizzled per 128B group; reads apply same XOR).
// Per iteration: vmcnt(4) [2 chunks stay in flight] -> raw s_barrier ->
// compute own-parity chunk -> lgkmcnt(0) + s_barrier -> DMA 2 chunks ahead.
__global__ __launch_bounds__(1024, 4) void k1_sims(const float* __restrict__ t_f,
                                                   const float* __restrict__ gal,
                                                   float2* __restrict__ partial) {
    __shared__ __align__(16) char gbuf[4][CHR * 2048];   // 131072 B ring

    const int tid = threadIdx.x;
    const int blk = blockIdx.x;
    const int lane = tid & 63;
    const int w = tid >> 6;          // 0..15
    const int bt = w & 7;            // b-tile
    const int par = w >> 3;          // chunk parity this wave computes
    const int l15 = lane & 15;
    const int l4 = lane >> 4;
    const int xr = (l15 & 7) << 4;

    const char* gal_b = reinterpret_cast<const char*>(gal);
    const size_t rowbase = (size_t)blk * GPB * 2048;
    const int lsw = (lane * 16) ^ ((w & 7) << 4);   // write swizzle, row = w

    // wave w stages row w of chunk c: 2 x 1KB contiguous DMA
#define DMA(c) do { \
        const char* s_ = gal_b + rowbase + ((size_t)(c) * CHR + w) * 2048 + lsw; \
        char* d_ = &gbuf[(c) & 3][w * 2048]; \
        __builtin_amdgcn_global_load_lds((as1cu8*)s_, (as3u8*)d_, 16, 0, 0); \
        __builtin_amdgcn_global_load_lds((as1cu8*)(s_ + 1024), (as3u8*)(d_ + 1024), 16, 0, 0); \
    } while (0)

    // prologue: 4 chunks in flight (8 insts/wave)
    DMA(0); DMA(1); DMA(2); DMA(3);

    // t-fragments (B operand): lane holds t[bt*16 + l15][ks*32 + l4*8 ..+8]
    short8 tfr[16];
    {
        const float* tp = t_f + (size_t)(bt * 16 + l15) * D + l4 * 8;
        #pragma unroll
        for (int ks = 0; ks < 16; ++ks) {
            float4 a = *reinterpret_cast<const float4*>(tp + ks * 32);
            float4 b = *reinterpret_cast<const float4*>(tp + ks * 32 + 4);
            uint4 q;
            q.x = pack_bf2(a.x, a.y); q.y = pack_bf2(a.z, a.w);
            q.z = pack_bf2(b.x, b.y); q.w = pack_bf2(b.z, b.w);
            tfr[ks] = *reinterpret_cast<short8*>(&q);
        }
    }

    float lst[K];
    #pragma unroll
    for (int k = 0; k < K; ++k) lst[k] = -1e30f;

    // compute chunk c (runtime parity offset): A = gallery rows (row=l15),
    // C layout: row(g) = l4*4+r, col(b) = l15.
#define COMPUTE(c) do { \
        f32x4 acc_ = (f32x4)0.0f; \
        float nrm_ = 0.0f; \
        const char* gb_ = &gbuf[(c) & 3][0]; \
        _Pragma("unroll") \
        for (int ks_ = 0; ks_ < 16; ++ks_) { \
            const int co_ = ks_ * 128 + l4 * 32; \
            float4 a0_ = *reinterpret_cast<const float4*>(gb_ + l15 * 2048 + (co_ ^ xr)); \
            float4 a1_ = *reinterpret_cast<const float4*>(gb_ + l15 * 2048 + ((co_ + 16) ^ xr)); \
            nrm_ = fmaf(a0_.x, a0_.x, nrm_); nrm_ = fmaf(a0_.y, a0_.y, nrm_); \
            nrm_ = fmaf(a0_.z, a0_.z, nrm_); nrm_ = fmaf(a0_.w, a0_.w, nrm_); \
            nrm_ = fmaf(a1_.x, a1_.x, nrm_); nrm_ = fmaf(a1_.y, a1_.y, nrm_); \
            nrm_ = fmaf(a1_.z, a1_.z, nrm_); nrm_ = fmaf(a1_.w, a1_.w, nrm_); \
            uint4 q_; \
            q_.x = pack_bf2(a0_.x, a0_.y); q_.y = pack_bf2(a0_.z, a0_.w); \
            q_.z = pack_bf2(a1_.x, a1_.y); q_.w = pack_bf2(a1_.z, a1_.w); \
            short8 af_ = *reinterpret_cast<short8*>(&q_); \
            acc_ = __builtin_amdgcn_mfma_f32_16x16x32_bf16(af_, tfr[ks_], acc_, 0, 0, 0); \
        } \
        nrm_ += __shfl_xor(nrm_, 16); \
        nrm_ += __shfl_xor(nrm_, 32); \
        float invn_ = rsqrtf(fmaxf(nrm_, 1e-24f)); \
        _Pragma("unroll") \
        for (int r_ = 0; r_ < 4; ++r_) { \
            float s_ = acc_[r_] * __shfl(invn_, l4 * 4 + r_); \
            unsigned meta_ = (unsigned)((c) * CHR + l4 * 4 + r_); \
            float sp_ = __uint_as_float((__float_as_uint(s_) & 0xFFFFFF00u) | meta_); \
            pk_insert(sp_, lst); \
        } \
    } while (0)

    // iteration: chunks 2i (even waves) and 2i+1 (odd waves) retire together.
#define ITER(i, vmn) \
    asm volatile("s_waitcnt vmcnt(" #vmn ")" ::: "memory"); \
    __builtin_amdgcn_sched_barrier(0); \
    __builtin_amdgcn_s_barrier(); \
    __builtin_amdgcn_sched_barrier(0); \
    COMPUTE(2 * (i) + par); \
    asm volatile("s_waitcnt lgkmcnt(0)" ::: "memory"); \
    __builtin_amdgcn_sched_barrier(0); \
    __builtin_amdgcn_s_barrier(); \
    __builtin_amdgcn_sched_barrier(0); \
    if (2 * (i) + 5 < NCHK) { DMA(2 * (i) + 4); DMA(2 * (i) + 5); }

    ITER(0, 4) ITER(1, 4) ITER(2, 4) ITER(3, 4)
    ITER(4, 4) ITER(5, 4) ITER(6, 4) ITER(7, 0)

#undef ITER
#undef COMPUTE
#undef DMA

    // merge per-b lists across the 4 l4 lanes (same b = bt*16 + l15)
    #pragma unroll
    for (int mk = 16; mk <= 32; mk <<= 1) {
        float inc[K];
        #pragma unroll
        for (int k = 0; k < K; ++k) inc[k] = __shfl_xor(lst[k], mk);
        #pragma unroll
        for (int k = 0; k < K; ++k) pk_insert(inc[k], lst);
    }

    // cross-parity merge via LDS (ring reused; all reads complete)
    __syncthreads();
    float* mbuf = reinterpret_cast<float*>(&gbuf[0][0]);   // [16 waves][16 l15][K]
    if (l4 == 0) {
        #pragma unroll
        for (int k = 0; k < K; ++k) mbuf[(w * 16 + l15) * K + k] = lst[k];
    }
    __syncthreads();
    if (w < 8 && l4 == 0) {
        const int b = w * 16 + l15;
        float fin[K];
        #pragma unroll
        for (int k = 0; k < K; ++k) fin[k] = mbuf[(w * 16 + l15) * K + k];
        #pragma unroll
        for (int k = 0; k < K; ++k) pk_insert(mbuf[((w + 8) * 16 + l15) * K + k], fin);
        #pragma unroll
        for (int k = 0; k < K; ++k) {
            unsigned sp = __float_as_uint(fin[k]);
            int g = blk * GPB + (int)(sp & 0xFFu);
            partial[((size_t)b * NBLK1 + blk) * K + k] = make_float2(fin[k], __int_as_float(g));
        }
    }
}

// k2: merge 256 partial top-5 lists per batch row -> top_idx. Shuffle-first.
__global__ __launch_bounds__(512) void k2_merge(const float2* __restrict__ partial,
                                                int* __restrict__ top_idx) {
    __shared__ float2 wlist[8][K];
    const int b = blockIdx.x;
    const int p = threadIdx.x;
    const int lane = p & 63;
    const int w = p >> 6;

    float mv[K]; int mi[K];
    #pragma unroll
    for (int k = 0; k < K; ++k) { mv[k] = -1e30f; mi[k] = 0x7fffffff; }
    if (p < NBLK1) {
        #pragma unroll
        for (int k = 0; k < K; ++k) {
            float2 c = partial[((size_t)b * NBLK1 + p) * K + k];
            mv[k] = c.x; mi[k] = __float_as_int(c.y);
        }
    }
    #pragma unroll
    for (int mk = 1; mk <= 32; mk <<= 1) {
        float ov[K]; int oi[K];
        #pragma unroll
        for (int k = 0; k < K; ++k) { ov[k] = __shfl_xor(mv[k], mk); oi[k] = __shfl_xor(mi[k], mk); }
        #pragma unroll
        for (int k = 0; k < K; ++k) top5_insert(ov[k], oi[k], mv, mi);
    }
    if (lane == 0) {
        #pragma unroll
        for (int k = 0; k < K; ++k) wlist[w][k] = make_float2(mv[k], __int_as_float(mi[k]));
    }
    __syncthreads();
    if (w == 0) {
        #pragma unroll
        for (int k = 0; k < K; ++k) { mv[k] = -1e30f; mi[k] = 0x7fffffff; }
        if (lane < 8) {
            #pragma unroll
            for (int k = 0; k < K; ++k) {
                float2 c = wlist[lane][k];
                mv[k] = c.x; mi[k] = __float_as_int(c.y);
            }
        }
        #pragma unroll
        for (int mk = 1; mk <= 4; mk <<= 1) {
            float ov[K]; int oi[K];
            #pragma unroll
            for (int k = 0; k < K; ++k) { ov[k] = __shfl_xor(mv[k], mk); oi[k] = __shfl_xor(mi[k], mk); }
            #pragma unroll
            for (int k = 0; k < K; ++k) top5_insert(ov[k], oi[k], mv, mi);
        }
        if (lane == 0) {
            #pragma unroll
            for (int k = 0; k < K; ++k) top_idx[b * K + k] = mi[k];
        }
    }
}

// k3: one block per (b,k) row: bottom-m membership of |gal[row,c]*s_f[b,c]|
// (per-row norms are positive constants -> ordering matches the reference's
// normalized products). Plain stores; kernel-boundary coherence (R8 lesson).
__global__ __launch_bounds__(512) void k3_member(const float* __restrict__ s_f,
                                                 const float* __restrict__ gal,
                                                 const int* __restrict__ top_idx,
                                                 unsigned long long* __restrict__ bkmask) {
    __shared__ __align__(16) float pS[D];
    const int p = threadIdx.x;
    const int bk = blockIdx.x;
    const int b = bk / K;
    const int row = top_idx[bk];
    float pv = fabsf(gal[(size_t)row * D + p] * s_f[(size_t)b * D + p]);
    pS[p] = pv;
    __syncthreads();
    int cnt = 0;
    const float4* p4 = reinterpret_cast<const float4*>(pS);
    #pragma unroll 4
    for (int j = 0; j < D / 4; ++j) {
        float4 o = p4[j];
        cnt += (o.x < pv || (o.x == pv && (4 * j + 0) < p)) ? 1 : 0;
        cnt += (o.y < pv || (o.y == pv && (4 * j + 1) < p)) ? 1 : 0;
        cnt += (o.z < pv || (o.z == pv && (4 * j + 2) < p)) ? 1 : 0;
        cnt += (o.w < pv || (o.w == pv && (4 * j + 3) < p)) ? 1 : 0;
    }
    unsigned long long bm = __ballot(cnt < M);
    if ((p & 63) == 0) bkmask[(size_t)bk * 8 + (p >> 6)] = bm;
}

// k4: AND-reduce the 640 per-(b,k) masks, emit the output mask. 40 KB, L2-hot.
__global__ __launch_bounds__(512) void k4_final(const unsigned long long* __restrict__ bkmask,
                                                float* __restrict__ out) {
    const int c = threadIdx.x;
    const int word = c >> 6, bit = c & 63;
    unsigned long long acc = ~0ull;
    for (int bk = 0; bk < B * K; bk += 4) {
        acc &= bkmask[(size_t)bk * 8 + word];
        acc &= bkmask[(size_t)(bk + 1) * 8 + word];
        acc &= bkmask[(size_t)(bk + 2) * 8 + word];
        acc &= bkmask[(size_t)(bk + 3) * 8 + word];
    }
    out[c] = ((acc >> bit) & 1ull) ? 0.0f : 1.0f;
}

extern "C" void kernel_launch(void* const* d_in, const int* in_sizes, int n_in,
                              void* d_out, int out_size, void* d_ws, size_t ws_size,
                              hipStream_t stream) {
    (void)in_sizes; (void)n_in; (void)out_size; (void)ws_size;
    const float* s_f = (const float*)d_in[0];
    const float* t_f = (const float*)d_in[1];
    const float* gal = (const float*)d_in[2];
    float* out = (float*)d_out;

    char* ws = (char*)d_ws;
    const size_t off_partial = 0;                        // 128*256*5*8 = 1310720
    const size_t off_topidx  = off_partial + 1310720;    // 2560
    const size_t off_bkmask  = off_topidx + 2560;        // 40960

    float2* partial = (float2*)(ws + off_partial);
    int* top_idx = (int*)(ws + off_topidx);
    unsigned long long* bkmask = (unsigned long long*)(ws + off_bkmask);

    hipLaunchKernelGGL(k1_sims, dim3(NBLK1), dim3(1024), 0, stream, t_f, gal, partial);
    hipLaunchKernelGGL(k2_merge, dim3(B), dim3(512), 0, stream, partial, top_idx);
    hipLaunchKernelGGL(k3_member, dim3(B * K), dim3(512), 0, stream, s_f, gal, top_idx, bkmask);
    hipLaunchKernelGGL(k4_final, dim3(1), dim3(512), 0, stream, bkmask, out);
}

// Round 15
// 137.749 us; speedup vs baseline: 1.2552x; 1.1550x over previous
//
#include <hip/hip_runtime.h>

#define B 128
#define N 65536
#define D 512
#define K 5
#define M 256              // D * RATIO
#define GPB 256            // gallery rows per block (kernel1)
#define NBLK1 (N / GPB)    // 256 blocks
#define CHR 16             // g-rows per chunk (full D each)
#define NCHK (GPB / CHR)   // 16

typedef __attribute__((ext_vector_type(8))) short short8;
typedef __attribute__((ext_vector_type(4))) float f32x4;
typedef __attribute__((address_space(1))) const unsigned char as1cu8;
typedef __attribute__((address_space(3))) unsigned char as3u8;

// pack two fp32 -> one u32 of 2 bf16 (truncation) via v_perm_b32.
__device__ __forceinline__ unsigned int pack_bf2(float lo, float hi) {
    return __builtin_amdgcn_perm(__float_as_uint(hi), __float_as_uint(lo), 0x07060302u);
}

__device__ __forceinline__ void top5_insert(float v, int gi, float tv[K], int ti[K]) {
    // descending by value, ties broken by lower index (matches lax.top_k)
    if (v > tv[K - 1] || (v == tv[K - 1] && gi < ti[K - 1])) {
        tv[K - 1] = v; ti[K - 1] = gi;
        #pragma unroll
        for (int k = K - 1; k > 0; --k) {
            bool sw = (tv[k] > tv[k - 1]) || (tv[k] == tv[k - 1] && ti[k] < ti[k - 1]);
            if (sw) {
                float fv = tv[k]; tv[k] = tv[k - 1]; tv[k - 1] = fv;
                int fi = ti[k]; ti[k] = ti[k - 1]; ti[k - 1] = fi;
            }
        }
    }
}

// packed-score insert (meta lives in low 8 mantissa bits; candidates distinct)
__device__ __forceinline__ void pk_insert(float sp, float lst[K]) {
    if (sp > lst[K - 1]) {
        lst[K - 1] = sp;
        #pragma unroll
        for (int k = K - 1; k > 0; --k)
            if (lst[k] > lst[k - 1]) {
                float t2 = lst[k]; lst[k] = lst[k - 1]; lst[k - 1] = t2;
            }
    }
}

// k1: R12's 16-wave kh-split shape (fits the empirical 64-VGPR cap of
// 1024-thread blocks: tfr[8]=32 regs/wave, no spills) + R13/R14's counted
// vmcnt discipline (chunks c+1,c+2 stay in flight across barriers; NO
// per-chunk vmcnt(0) drain — R12's one flaw). 3-deep LDS ring. Waves
// (bt,kh): kh half-K MFMA partials exchanged via cbuf one chunk behind;
// kh==1 waves do the finish (sum halves, scale by rsqrt norm, top-5).
__global__ __launch_bounds__(1024) void k1_sims(const float* __restrict__ t_f,
                                                const float* __restrict__ gal,
                                                float2* __restrict__ partial) {
    __shared__ __align__(16) char gbuf[3][CHR * 2048];   // 98304 B ring
    __shared__ __align__(16) float cbuf_c[2][16][256];   // 32768 B C exchange
    __shared__ __align__(16) float cbuf_n[2][16][16];    //  2048 B norm exchange

    const int tid = threadIdx.x;
    const int blk = blockIdx.x;
    const int lane = tid & 63;
    const int w = tid >> 6;          // 0..15
    const int bt = w & 7;            // b-tile
    const int kh = w >> 3;           // k-half
    const int l15 = lane & 15;
    const int l4 = lane >> 4;
    const int xr = (l15 & 7) << 4;

    const char* gal_b = reinterpret_cast<const char*>(gal);
    const size_t rowbase = (size_t)blk * GPB * 2048;
    const int lsw = (lane * 16) ^ ((w & 7) << 4);   // write swizzle (row = w)

    // t-fragments FIRST (their consumption waits must not drain the DMA ring):
    // lane holds t[bt*16 + l15][ks*32 + l4*8 ..+8], ks = kh*8+j. 32 VGPR.
    short8 tfr[8];
    {
        const float* tp = t_f + (size_t)(bt * 16 + l15) * D + (kh * 8) * 32 + l4 * 8;
        #pragma unroll
        for (int j = 0; j < 8; ++j) {
            float4 a = *reinterpret_cast<const float4*>(tp + j * 32);
            float4 b = *reinterpret_cast<const float4*>(tp + j * 32 + 4);
            uint4 q;
            q.x = pack_bf2(a.x, a.y); q.y = pack_bf2(a.z, a.w);
            q.z = pack_bf2(b.x, b.y); q.w = pack_bf2(b.z, b.w);
            tfr[j] = *reinterpret_cast<short8*>(&q);
        }
    }
    __builtin_amdgcn_sched_barrier(0);

    // wave w stages row w of chunk c: 2 x 1KB contiguous DMA, swizzled source
#define DMA(c) do { \
        const char* s_ = gal_b + rowbase + ((size_t)(c) * CHR + w) * 2048 + lsw; \
        char* d_ = &gbuf[(c) % 3][w * 2048]; \
        __builtin_amdgcn_global_load_lds((as1cu8*)s_, (as3u8*)d_, 16, 0, 0); \
        __builtin_amdgcn_global_load_lds((as1cu8*)(s_ + 1024), (as3u8*)(d_ + 1024), 16, 0, 0); \
    } while (0)

    DMA(0); DMA(1); DMA(2);   // 6 ops/wave in flight

    float lst[K];
    #pragma unroll
    for (int k = 0; k < K; ++k) lst[k] = -1e30f;

    // compute chunk c (this wave's k-half): A = g-rows (row=l15), C row(g)=l4*4+r
#define COMPUTE(c) do { \
        f32x4 acc_ = (f32x4)0.0f; \
        float nrm_ = 0.0f; \
        const char* gb_ = &gbuf[(c) % 3][0]; \
        _Pragma("unroll") \
        for (int j_ = 0; j_ < 8; ++j_) { \
            const int co_ = (kh * 8 + j_) * 128 + l4 * 32; \
            float4 a0_ = *reinterpret_cast<const float4*>(gb_ + l15 * 2048 + (co_ ^ xr)); \
            float4 a1_ = *reinterpret_cast<const float4*>(gb_ + l15 * 2048 + ((co_ + 16) ^ xr)); \
            nrm_ = fmaf(a0_.x, a0_.x, nrm_); nrm_ = fmaf(a0_.y, a0_.y, nrm_); \
            nrm_ = fmaf(a0_.z, a0_.z, nrm_); nrm_ = fmaf(a0_.w, a0_.w, nrm_); \
            nrm_ = fmaf(a1_.x, a1_.x, nrm_); nrm_ = fmaf(a1_.y, a1_.y, nrm_); \
            nrm_ = fmaf(a1_.z, a1_.z, nrm_); nrm_ = fmaf(a1_.w, a1_.w, nrm_); \
            uint4 q_; \
            q_.x = pack_bf2(a0_.x, a0_.y); q_.y = pack_bf2(a0_.z, a0_.w); \
            q_.z = pack_bf2(a1_.x, a1_.y); q_.w = pack_bf2(a1_.z, a1_.w); \
            short8 af_ = *reinterpret_cast<short8*>(&q_); \
            acc_ = __builtin_amdgcn_mfma_f32_16x16x32_bf16(af_, tfr[j_], acc_, 0, 0, 0); \
        } \
        nrm_ += __shfl_xor(nrm_, 16); \
        nrm_ += __shfl_xor(nrm_, 32); \
        if (lane < CHR) cbuf_n[(c) & 1][w][lane] = nrm_; \
        *reinterpret_cast<f32x4*>(&cbuf_c[(c) & 1][w][lane * 4]) = acc_; \
    } while (0)

    // finish chunk c (kh==1 waves): sum k-halves, scale, top-5 insert
#define FINISH(c) do { \
        const int pb_ = (c) & 1; \
        f32x4 c0_ = *reinterpret_cast<const f32x4*>(&cbuf_c[pb_][bt][lane * 4]); \
        f32x4 c1_ = *reinterpret_cast<const f32x4*>(&cbuf_c[pb_][8 + bt][lane * 4]); \
        float4 n0_ = *reinterpret_cast<const float4*>(&cbuf_n[pb_][bt][l4 * 4]); \
        float4 n1_ = *reinterpret_cast<const float4*>(&cbuf_n[pb_][8 + bt][l4 * 4]); \
        float nn_[4] = {n0_.x + n1_.x, n0_.y + n1_.y, n0_.z + n1_.z, n0_.w + n1_.w}; \
        _Pragma("unroll") \
        for (int r_ = 0; r_ < 4; ++r_) { \
            float s_ = (c0_[r_] + c1_[r_]) * rsqrtf(fmaxf(nn_[r_], 1e-24f)); \
            unsigned meta_ = (unsigned)((c) * CHR + l4 * 4 + r_); \
            float sp_ = __uint_as_float((__float_as_uint(s_) & 0xFFFFFF00u) | meta_); \
            pk_insert(sp_, lst); \
        } \
    } while (0)

#define ITER(c, vmn) \
    asm volatile("s_waitcnt vmcnt(" #vmn ")" ::: "memory"); \
    __builtin_amdgcn_sched_barrier(0); \
    __builtin_amdgcn_s_barrier(); \
    __builtin_amdgcn_sched_barrier(0); \
    if ((c) > 0 && kh == 1) FINISH((c) - 1); \
    COMPUTE(c); \
    asm volatile("s_waitcnt lgkmcnt(0)" ::: "memory"); \
    __builtin_amdgcn_sched_barrier(0); \
    __builtin_amdgcn_s_barrier(); \
    __builtin_amdgcn_sched_barrier(0); \
    if ((c) + 3 < NCHK) DMA((c) + 3);

    ITER(0, 4)  ITER(1, 4)  ITER(2, 4)  ITER(3, 4)
    ITER(4, 4)  ITER(5, 4)  ITER(6, 4)  ITER(7, 4)
    ITER(8, 4)  ITER(9, 4)  ITER(10, 4) ITER(11, 4)
    ITER(12, 4) ITER(13, 4) ITER(14, 2) ITER(15, 0)

    if (kh == 1) {
        FINISH(15);
        // merge per-b lists across the 4 l4 lanes (same b = bt*16 + l15)
        #pragma unroll
        for (int mk = 16; mk <= 32; mk <<= 1) {
            float inc[K];
            #pragma unroll
            for (int k = 0; k < K; ++k) inc[k] = __shfl_xor(lst[k], mk);
            #pragma unroll
            for (int k = 0; k < K; ++k) pk_insert(inc[k], lst);
        }
        if (l4 == 0) {
            const int b = bt * 16 + l15;
            #pragma unroll
            for (int k = 0; k < K; ++k) {
                unsigned sp = __float_as_uint(lst[k]);
                int g = blk * GPB + (int)(sp & 0xFFu);
                partial[((size_t)b * NBLK1 + blk) * K + k] = make_float2(lst[k], __int_as_float(g));
            }
        }
    }
#undef ITER
#undef FINISH
#undef COMPUTE
#undef DMA
}

// k2: merge 256 partial top-5 lists per batch row -> top_idx. Shuffle-first.
__global__ __launch_bounds__(512) void k2_merge(const float2* __restrict__ partial,
                                                int* __restrict__ top_idx) {
    __shared__ float2 wlist[8][K];
    const int b = blockIdx.x;
    const int p = threadIdx.x;
    const int lane = p & 63;
    const int w = p >> 6;

    float mv[K]; int mi[K];
    #pragma unroll
    for (int k = 0; k < K; ++k) { mv[k] = -1e30f; mi[k] = 0x7fffffff; }
    if (p < NBLK1) {
        #pragma unroll
        for (int k = 0; k < K; ++k) {
            float2 c = partial[((size_t)b * NBLK1 + p) * K + k];
            mv[k] = c.x; mi[k] = __float_as_int(c.y);
        }
    }
    #pragma unroll
    for (int mk = 1; mk <= 32; mk <<= 1) {
        float ov[K]; int oi[K];
        #pragma unroll
        for (int k = 0; k < K; ++k) { ov[k] = __shfl_xor(mv[k], mk); oi[k] = __shfl_xor(mi[k], mk); }
        #pragma unroll
        for (int k = 0; k < K; ++k) top5_insert(ov[k], oi[k], mv, mi);
    }
    if (lane == 0) {
        #pragma unroll
        for (int k = 0; k < K; ++k) wlist[w][k] = make_float2(mv[k], __int_as_float(mi[k]));
    }
    __syncthreads();
    if (w == 0) {
        #pragma unroll
        for (int k = 0; k < K; ++k) { mv[k] = -1e30f; mi[k] = 0x7fffffff; }
        if (lane < 8) {
            #pragma unroll
            for (int k = 0; k < K; ++k) {
                float2 c = wlist[lane][k];
                mv[k] = c.x; mi[k] = __float_as_int(c.y);
            }
        }
        #pragma unroll
        for (int mk = 1; mk <= 4; mk <<= 1) {
            float ov[K]; int oi[K];
            #pragma unroll
            for (int k = 0; k < K; ++k) { ov[k] = __shfl_xor(mv[k], mk); oi[k] = __shfl_xor(mi[k], mk); }
            #pragma unroll
            for (int k = 0; k < K; ++k) top5_insert(ov[k], oi[k], mv, mi);
        }
        if (lane == 0) {
            #pragma unroll
            for (int k = 0; k < K; ++k) top_idx[b * K + k] = mi[k];
        }
    }
}

// k3: one block per (b,k) row: bottom-m membership of |gal[row,c]*s_f[b,c]|
// (per-row norms are positive constants -> ordering matches the reference's
// normalized products). Plain stores; kernel-boundary coherence (R8 lesson).
__global__ __launch_bounds__(512) void k3_member(const float* __restrict__ s_f,
                                                 const float* __restrict__ gal,
                                                 const int* __restrict__ top_idx,
                                                 unsigned long long* __restrict__ bkmask) {
    __shared__ __align__(16) float pS[D];
    const int p = threadIdx.x;
    const int bk = blockIdx.x;
    const int b = bk / K;
    const int row = top_idx[bk];
    float pv = fabsf(gal[(size_t)row * D + p] * s_f[(size_t)b * D + p]);
    pS[p] = pv;
    __syncthreads();
    int cnt = 0;
    const float4* p4 = reinterpret_cast<const float4*>(pS);
    #pragma unroll 4
    for (int j = 0; j < D / 4; ++j) {
        float4 o = p4[j];
        cnt += (o.x < pv || (o.x == pv && (4 * j + 0) < p)) ? 1 : 0;
        cnt += (o.y < pv || (o.y == pv && (4 * j + 1) < p)) ? 1 : 0;
        cnt += (o.z < pv || (o.z == pv && (4 * j + 2) < p)) ? 1 : 0;
        cnt += (o.w < pv || (o.w == pv && (4 * j + 3) < p)) ? 1 : 0;
    }
    unsigned long long bm = __ballot(cnt < M);
    if ((p & 63) == 0) bkmask[(size_t)bk * 8 + (p >> 6)] = bm;
}

// k4: AND-reduce the 640 per-(b,k) masks, emit the output mask. 40 KB, L2-hot.
__global__ __launch_bounds__(512) void k4_final(const unsigned long long* __restrict__ bkmask,
                                                float* __restrict__ out) {
    const int c = threadIdx.x;
    const int word = c >> 6, bit = c & 63;
    unsigned long long acc = ~0ull;
    for (int bk = 0; bk < B * K; bk += 4) {
        acc &= bkmask[(size_t)bk * 8 + word];
        acc &= bkmask[(size_t)(bk + 1) * 8 + word];
        acc &= bkmask[(size_t)(bk + 2) * 8 + word];
        acc &= bkmask[(size_t)(bk + 3) * 8 + word];
    }
    out[c] = ((acc >> bit) & 1ull) ? 0.0f : 1.0f;
}

extern "C" void kernel_launch(void* const* d_in, const int* in_sizes, int n_in,
                              void* d_out, int out_size, void* d_ws, size_t ws_size,
                              hipStream_t stream) {
    (void)in_sizes; (void)n_in; (void)out_size; (void)ws_size;
    const float* s_f = (const float*)d_in[0];
    const float* t_f = (const float*)d_in[1];
    const float* gal = (const float*)d_in[2];
    float* out = (float*)d_out;

    char* ws = (char*)d_ws;
    const size_t off_partial = 0;                        // 128*256*5*8 = 1310720
    const size_t off_topidx  = off_partial + 1310720;    // 2560
    const size_t off_bkmask  = off_topidx + 2560;        // 40960

    float2* partial = (float2*)(ws + off_partial);
    int* top_idx = (int*)(ws + off_topidx);
    unsigned long long* bkmask = (unsigned long long*)(ws + off_bkmask);

    hipLaunchKernelGGL(k1_sims, dim3(NBLK1), dim3(1024), 0, stream, t_f, gal, partial);
    hipLaunchKernelGGL(k2_merge, dim3(B), dim3(512), 0, stream, partial, top_idx);
    hipLaunchKernelGGL(k3_member, dim3(B * K), dim3(512), 0, stream, s_f, gal, top_idx, bkmask);
    hipLaunchKernelGGL(k4_final, dim3(1), dim3(512), 0, stream, bkmask, out);
}